// Round 13
// baseline (212.629 us; speedup 1.0000x reference)
//
#include <hip/hip_runtime.h>
#include <hip/hip_bf16.h>

#define B_N 16384
#define TAU 0.25f
#define GS 68     // G leading dim (floats); 16B-aligned rows
#define YS 133    // Y leading dim (floats); ODD -> scalar access conflict-free

typedef float f32x4 __attribute__((ext_vector_type(4)));
typedef short s16x8 __attribute__((ext_vector_type(8)));

__device__ __forceinline__ void gl_lds16(const void* g, void* l) {
    __builtin_amdgcn_global_load_lds(
        (const __attribute__((address_space(1))) void*)g,
        (__attribute__((address_space(3))) void*)l, 16, 0, 0);
}

__device__ __forceinline__ unsigned short bf16_bits(float v) {
    __hip_bfloat16 h = __float2bfloat16(v);
    return *reinterpret_cast<unsigned short*>(&h);
}

// ---------------------------------------------------------------------------
// Kernel 1 (merged): blocks 0..63 = per-cluster prep; blocks 64..319 = convert.
// (identical to R9-R12 except: block 64 also zeroes the 128 m-tile counters)
// ---------------------------------------------------------------------------
__global__ __launch_bounds__(256) void prep_convert(const float* __restrict__ x,
                                                    const float* __restrict__ D,
                                                    unsigned short* __restrict__ xh,
                                                    float* __restrict__ nrm,
                                                    float* __restrict__ Qg,
                                                    unsigned short* __restrict__ Bht,
                                                    int* __restrict__ mcnt,
                                                    float* __restrict__ out) {
    const int t = threadIdx.x;

    if (blockIdx.x >= 64) {
        // ---------------- convert path ----------------
        const int gid = (blockIdx.x - 64) * 256 + t;   // 0..65535 quarter-rows
        if (gid == 0) out[0] = 0.0f;
        if (blockIdx.x == 64 && t < 128) mcnt[t] = 0;   // ws is 0xAA-poisoned
        const size_t base = (size_t)gid * 32;
        float s = 0.0f;
        #pragma unroll
        for (int c = 0; c < 8; ++c) {
            const f32x4 v = ((const f32x4*)(x + base))[c];
            s += v.x * v.x + v.y * v.y + v.z * v.z + v.w * v.w;
            ushort4 h;
            h.x = bf16_bits(v.x); h.y = bf16_bits(v.y);
            h.z = bf16_bits(v.z); h.w = bf16_bits(v.w);
            ((ushort4*)(xh + base))[c] = h;
        }
        s += __shfl_xor(s, 1, 64);
        s += __shfl_xor(s, 2, 64);
        if ((gid & 3) == 0) nrm[gid >> 2] = s;
        return;
    }

    // ---------------- prep path ----------------
    __shared__ float Y[64 * YS];                      // D^T -> Q^T (in place)
    __shared__ __align__(16) float G[64 * GS + 64];   // gram -> L; tail = 1/L[i][i]
    __shared__ __align__(16) float Lti[8 * 8 * 8];    // 8x8 diag-block inverses
    const int n = blockIdx.x;
    const float* Dn = D + (size_t)n * 8192;

    // Phase A: Y[j][c] = Dn[c][j]
    for (int e4 = t; e4 < 2048; e4 += 256) {
        const int c = e4 >> 4, j4 = (e4 & 15) * 4;
        const f32x4 v = ((const f32x4*)Dn)[e4];
        Y[(j4 + 0) * YS + c] = v.x;
        Y[(j4 + 1) * YS + c] = v.y;
        Y[(j4 + 2) * YS + c] = v.z;
        Y[(j4 + 3) * YS + c] = v.w;
    }

    // Phase B: gram from global
    {
        const int a0 = (t & 15) * 4, b0 = (t >> 4) * 4;
        float acc[4][4] = {};
        #pragma unroll 4
        for (int i = 0; i < 128; ++i) {
            const f32x4 av = *(const f32x4*)(Dn + i * 64 + a0);
            const f32x4 bv = *(const f32x4*)(Dn + i * 64 + b0);
            const float aa[4] = {av.x, av.y, av.z, av.w};
            const float bb[4] = {bv.x, bv.y, bv.z, bv.w};
            #pragma unroll
            for (int p = 0; p < 4; ++p)
                #pragma unroll
                for (int q = 0; q < 4; ++q) acc[p][q] = fmaf(aa[p], bb[q], acc[p][q]);
        }
        #pragma unroll
        for (int p = 0; p < 4; ++p)
            #pragma unroll
            for (int q = 0; q < 4; ++q) G[(a0 + p) * GS + b0 + q] = acc[p][q];
    }
    __syncthreads();

    // Phase C: blocked Cholesky
    for (int p8 = 0; p8 < 8; ++p8) {
        const int pb = p8 * 8;
        if (t < 64) {
            const int lane = t;
            const f32x4 v0 = *(const f32x4*)&G[lane * GS + pb];
            const f32x4 v1 = *(const f32x4*)&G[lane * GS + pb + 4];
            float g[8] = {v0.x, v0.y, v0.z, v0.w, v1.x, v1.y, v1.z, v1.w};
            #pragma unroll
            for (int kk = 0; kk < 8; ++kk) {
                const int k = pb + kk;
                const float dk = __shfl(g[kk], k, 64);
                const float rinv = 1.0f / sqrtf(dk);
                const float lik = g[kk] * rinv;
                g[kk] = lik;
                if (lane == 0) G[64 * GS + k] = rinv;
                #pragma unroll
                for (int jj = kk + 1; jj < 8; ++jj) {
                    const float ljk = __shfl(lik, pb + jj, 64);
                    g[jj] -= lik * ljk;
                }
            }
            *(f32x4*)&G[lane * GS + pb]     = (f32x4){g[0], g[1], g[2], g[3]};
            *(f32x4*)&G[lane * GS + pb + 4] = (f32x4){g[4], g[5], g[6], g[7]};
        }
        __syncthreads();
        const int base = pb + 8;
        if (base < 64) {
            for (int i = base + (t >> 5); i < 64; i += 8) {
                const f32x4 Li0 = *(const f32x4*)&G[i * GS + pb];
                const f32x4 Li1 = *(const f32x4*)&G[i * GS + pb + 4];
                for (int j = base + (t & 31); j < 64; j += 32) {
                    const f32x4 Lj0 = *(const f32x4*)&G[j * GS + pb];
                    const f32x4 Lj1 = *(const f32x4*)&G[j * GS + pb + 4];
                    float s = G[i * GS + j];
                    s -= Li0.x * Lj0.x + Li0.y * Lj0.y + Li0.z * Lj0.z + Li0.w * Lj0.w;
                    s -= Li1.x * Lj1.x + Li1.y * Lj1.y + Li1.z * Lj1.z + Li1.w * Lj1.w;
                    G[i * GS + j] = s;
                }
            }
        }
        __syncthreads();
    }

    // Phase D: invert 8x8 diagonal blocks
    if (t < 64) {
        const int bi = t >> 3, c = t & 7;
        const int base = bi * 8;
        float m[8];
        #pragma unroll
        for (int r = 0; r < 8; ++r) {
            float s = (r == c) ? 1.0f : 0.0f;
            #pragma unroll
            for (int k = 0; k < r; ++k)
                s -= G[(base + r) * GS + base + k] * m[k];
            m[r] = s * G[64 * GS + base + r];
        }
        #pragma unroll
        for (int r = 0; r < 8; ++r) Lti[(base + r) * 8 + c] = m[r];
    }
    __syncthreads();

    // Phase E: block forward substitution
    if (t < 128) {
        const int c = t;
        for (int i = 0; i < 8; ++i) {
            float Tv[8];
            #pragma unroll
            for (int r = 0; r < 8; ++r) Tv[r] = Y[(i * 8 + r) * YS + c];
            for (int k = 0; k < i; ++k) {
                #pragma unroll
                for (int kk = 0; kk < 8; ++kk) {
                    const float z = Y[(k * 8 + kk) * YS + c];
                    #pragma unroll
                    for (int r = 0; r < 8; ++r)
                        Tv[r] -= G[(i * 8 + r) * GS + k * 8 + kk] * z;
                }
            }
            #pragma unroll
            for (int r = 0; r < 8; ++r) {
                float z = 0.0f;
                #pragma unroll
                for (int rp = 0; rp <= r; ++rp)
                    z += Lti[(i * 8 + r) * 8 + rp] * Tv[rp];
                Y[(i * 8 + r) * YS + c] = z;
            }
        }
    }
    __syncthreads();

    // Phase F: outputs
    for (int e = t; e < 8192; e += 256) {
        const int j = e >> 7, i = e & 127;
        Bht[((size_t)n * 64 + j) * 128 + i] = bf16_bits(Y[j * YS + i]);
    }
    for (int e = t; e < 8192; e += 256) {
        const int i = e >> 6, j = e & 63;
        Qg[(size_t)n * 8192 + e] = Y[j * YS + i];
    }
}

// ---------------------------------------------------------------------------
// Kernel 2: GEMM scores + last-block-per-m-tile argmax/loss/rescore.
// Grid (128 m-tiles x 4 n-splits) = 512 blocks -> 2 blocks/CU (the occupancy
// the R10-R12 fused variants lacked). A-frags direct from global (R12-proven);
// B double-buffered LDS (2x32 KB) with early DMA kick, ONE barrier/iter.
// After writing its Sa slice each block fences + bumps mcnt[mtile]; the 4th
// arriver re-reads the 32 KB score set (L2) and does argmax+loss+rescore.
// ---------------------------------------------------------------------------
__global__ __launch_bounds__(256) void gemm_fused(
        const unsigned short* __restrict__ xh,
        const unsigned short* __restrict__ Bht,
        float* __restrict__ Sa,
        const float* __restrict__ nrm,
        const float* __restrict__ x,
        const float* __restrict__ Qg,
        int* __restrict__ mcnt,
        float* __restrict__ out) {
    __shared__ __align__(16) unsigned char lraw[66560];   // B0|B1; St aliases
    unsigned short* ldsB0 = (unsigned short*)lraw;         // 32 KB
    unsigned short* ldsB1 = (unsigned short*)(lraw + 32768); // 32 KB
    float* St = (float*)lraw;                              // [sample][69] 35.3 KB
    __shared__ int sflags[128];
    __shared__ int scnt, lastFlag;
    __shared__ float ssum[2];
    __shared__ float scorr[4];

    const int t = threadIdx.x, w = t >> 6, lane = t & 63;
    const int m0 = blockIdx.x * 128;
    const int nsplit = blockIdx.y;           // 16 clusters per split
    const int wm = w & 1, wn = w >> 1;
    const int lm = lane & 15, lg = lane >> 4;

    // ---- A-fragments direct from global (one-time, 64 VGPRs) ----
    s16x8 af[4][4];
    #pragma unroll
    for (int mt = 0; mt < 4; ++mt)
        #pragma unroll
        for (int ks = 0; ks < 4; ++ks)
            af[mt][ks] = *(const s16x8*)(xh +
                (size_t)(m0 + wm * 64 + mt * 16 + lm) * 128 + ks * 32 + lg * 8);

    // ---- kick B tile 0 into B0 ----
    {
        const int rl = lane >> 4, p = lane & 15;
        #pragma unroll
        for (int q = 0; q < 8; ++q) {
            const int row = w * 32 + q * 4 + rl;
            const int c = p ^ (row & 15);
            gl_lds16(Bht + (size_t)(nsplit * 1024 + row) * 128 + c * 8,
                     &ldsB0[(w * 32 + q * 4) * 128]);
        }
    }
    __syncthreads();

    #pragma unroll 1
    for (int it = 0; it < 8; ++it) {
        unsigned short* cur = (it & 1) ? ldsB1 : ldsB0;
        unsigned short* nxt = (it & 1) ? ldsB0 : ldsB1;

        // early kick: tile it+1 into the idle buffer (drained at end barrier)
        if (it < 7) {
            const int rl = lane >> 4, p = lane & 15;
            #pragma unroll
            for (int q = 0; q < 8; ++q) {
                const int row = w * 32 + q * 4 + rl;
                const int c = p ^ (row & 15);
                gl_lds16(Bht + (size_t)(nsplit * 1024 + (it + 1) * 128 + row) * 128 + c * 8,
                         &nxt[(w * 32 + q * 4) * 128]);
            }
        }

        // frag reads from cur (staged by the previous iteration's DMA)
        s16x8 bf[4][4];
        #pragma unroll
        for (int nt = 0; nt < 4; ++nt) {
            const int r = wn * 64 + nt * 16 + lm;
            #pragma unroll
            for (int ks = 0; ks < 4; ++ks) {
                const int p = (ks * 4 + lg) ^ (r & 15);
                bf[nt][ks] = *(const s16x8*)&cur[r * 128 + p * 8];
            }
        }

        // MFMAs with interleaved per-mt epilogue -> Sa
        const int nc = nsplit * 16 + it * 2 + wn;
        #pragma unroll
        for (int mt = 0; mt < 4; ++mt) {
            f32x4 acc[4];
            #pragma unroll
            for (int nt = 0; nt < 4; ++nt) acc[nt] = (f32x4){0.f, 0.f, 0.f, 0.f};
            #pragma unroll
            for (int ks = 0; ks < 4; ++ks)
                #pragma unroll
                for (int nt = 0; nt < 4; ++nt)
                    acc[nt] = __builtin_amdgcn_mfma_f32_16x16x32_bf16(
                        af[mt][ks], bf[nt][ks], acc[nt], 0, 0, 0);
            #pragma unroll
            for (int rg = 0; rg < 4; ++rg) {
                float p = 0.0f;
                #pragma unroll
                for (int nt = 0; nt < 4; ++nt) {
                    const float v = acc[nt][rg];
                    p += v * v;
                }
                p += __shfl_xor(p, 1, 64);
                p += __shfl_xor(p, 2, 64);
                p += __shfl_xor(p, 4, 64);
                p += __shfl_xor(p, 8, 64);
                if (lm == 0)
                    Sa[(size_t)nc * B_N + m0 + wm * 64 + mt * 16 + lg * 4 + rg] = p;
            }
        }
        __syncthreads();   // drains this iter's kick; cur reads done
    }

    // ---- arrive; 4th block per m-tile does the tail ----
    __threadfence();
    if (t == 0) {
        const int old = __hip_atomic_fetch_add(&mcnt[blockIdx.x], 1,
                            __ATOMIC_ACQ_REL, __HIP_MEMORY_SCOPE_AGENT);
        lastFlag = (old == 3) ? 1 : 0;
        scnt = 0;
    }
    __syncthreads();
    if (!lastFlag) return;
    __threadfence();

    // load the m-tile's full score set: St[m][n], stride 69 (2-way max banks)
    for (int e = t; e < 8192; e += 256) {
        const int n = e >> 7, m = e & 127;
        St[m * 69 + n] = Sa[(size_t)n * B_N + m0 + m];
    }
    __syncthreads();

    // argmax + near-tie flags + loss (threads 0..127 = samples)
    if (t < 128) {
        float v1 = -1e30f, v2 = -1e30f;
        int n1 = 0;
        for (int n = 0; n < 64; ++n) {
            const float v = St[t * 69 + n];
            if (v > v1) { v2 = v1; v1 = v; n1 = n; }
            else v2 = fmaxf(v2, v);
        }
        out[1 + m0 + t] = (float)n1;
        if (v1 - v2 < TAU) { const int i = atomicAdd(&scnt, 1); sflags[i] = t; }
        float err = nrm[m0 + t] - v1;
        for (int off = 32; off; off >>= 1) err += __shfl_xor(err, off, 64);
        if (lane == 0) ssum[w] = err;
    }
    if (lane == 0) scorr[w] = 0.0f;
    __syncthreads();

    // cooperative exact fp32 rescore of flagged samples (lane = cluster)
    const int nf = scnt;
    float corr = 0.0f;
    for (int f = w; f < nf; f += 4) {
        const int s = sflags[f];
        const int b2 = m0 + s;
        const float v = St[s * 69 + lane];
        float vm = v;
        for (int off = 32; off; off >>= 1) vm = fmaxf(vm, __shfl_xor(vm, off, 64));
        unsigned long long mask = __ballot((vm - v) < TAU);
        float best = -1e30f;
        int bn = 0;
        while (mask) {
            const int nn = (int)__builtin_ctzll(mask);
            mask &= mask - 1;
            const float* Qn = Qg + (size_t)nn * 8192;
            const float* xb = x + (size_t)b2 * 128;
            float d0 = 0.0f, d1 = 0.0f, d2 = 0.0f, d3 = 0.0f;
            #pragma unroll
            for (int i = 0; i < 128; i += 4) {
                d0 = fmaf(Qn[(i + 0) * 64 + lane], xb[i + 0], d0);
                d1 = fmaf(Qn[(i + 1) * 64 + lane], xb[i + 1], d1);
                d2 = fmaf(Qn[(i + 2) * 64 + lane], xb[i + 2], d2);
                d3 = fmaf(Qn[(i + 3) * 64 + lane], xb[i + 3], d3);
            }
            const float dot = (d0 + d1) + (d2 + d3);
            float sv = dot * dot;
            for (int off = 32; off; off >>= 1) sv += __shfl_xor(sv, off, 64);
            if (sv > best) { best = sv; bn = nn; }
        }
        if (lane == 0) {
            out[1 + b2] = (float)bn;
            corr += vm - best;   // replace approx top score with exact best
        }
    }
    if (lane == 0 && corr != 0.0f) scorr[w] += corr;
    __syncthreads();
    if (t == 0)
        atomicAdd(out, ssum[0] + ssum[1] + scorr[0] + scorr[1] + scorr[2] + scorr[3]);
}

// ---------------------------------------------------------------------------
extern "C" void kernel_launch(void* const* d_in, const int* in_sizes, int n_in,
                              void* d_out, int out_size, void* d_ws, size_t ws_size,
                              hipStream_t stream) {
    const float* x = (const float*)d_in[0];   // [16384, 128]
    const float* D = (const float*)d_in[1];   // [64, 128, 64]
    float* out = (float*)d_out;               // [1 + 16384]

    char* ws = (char*)d_ws;
    unsigned short* xh  = (unsigned short*)(ws);                 // 4 MB
    unsigned short* Bht = (unsigned short*)(ws + (4u << 20));    // 1 MB
    float* Qg           = (float*)(ws + (5u << 20));             // 2 MB
    float* Sa           = (float*)(ws + (7u << 20));             // 4 MB
    float* nrm          = (float*)(ws + (11u << 20));            // 64 KB
    int* mcnt           = (int*)(ws + (11u << 20) + 65536);      // 512 B

    prep_convert<<<320, 256, 0, stream>>>(x, D, xh, nrm, Qg, Bht, mcnt, out);
    gemm_fused<<<dim3(128, 4), 256, 0, stream>>>(xh, Bht, Sa, nrm, x, Qg, mcnt, out);
}

// Round 14
// 159.422 us; speedup vs baseline: 1.3337x; 1.3337x over previous
//
#include <hip/hip_runtime.h>
#include <hip/hip_bf16.h>

#define B_N 16384
#define TAU 0.25f
#define GS 68     // G leading dim (floats); 16B-aligned rows
#define YS 133    // Y leading dim (floats); ODD -> scalar access conflict-free

typedef float f32x4 __attribute__((ext_vector_type(4)));
typedef short s16x8 __attribute__((ext_vector_type(8)));

__device__ __forceinline__ void gl_lds16(const void* g, void* l) {
    __builtin_amdgcn_global_load_lds(
        (const __attribute__((address_space(1))) void*)g,
        (__attribute__((address_space(3))) void*)l, 16, 0, 0);
}

__device__ __forceinline__ unsigned short bf16_bits(float v) {
    __hip_bfloat16 h = __float2bfloat16(v);
    return *reinterpret_cast<unsigned short*>(&h);
}

// ---------------------------------------------------------------------------
// Kernel 1 (merged): blocks 0..63 = per-cluster prep; blocks 64..319 = convert.
// (byte-identical to R9 — the 161-us best)
// ---------------------------------------------------------------------------
__global__ __launch_bounds__(256) void prep_convert(const float* __restrict__ x,
                                                    const float* __restrict__ D,
                                                    unsigned short* __restrict__ xh,
                                                    float* __restrict__ nrm,
                                                    float* __restrict__ Qg,
                                                    unsigned short* __restrict__ Bht,
                                                    float* __restrict__ out) {
    const int t = threadIdx.x;

    if (blockIdx.x >= 64) {
        // ---------------- convert path ----------------
        const int gid = (blockIdx.x - 64) * 256 + t;   // 0..65535 quarter-rows
        if (gid == 0) out[0] = 0.0f;
        const size_t base = (size_t)gid * 32;
        float s = 0.0f;
        #pragma unroll
        for (int c = 0; c < 8; ++c) {
            const f32x4 v = ((const f32x4*)(x + base))[c];
            s += v.x * v.x + v.y * v.y + v.z * v.z + v.w * v.w;
            ushort4 h;
            h.x = bf16_bits(v.x); h.y = bf16_bits(v.y);
            h.z = bf16_bits(v.z); h.w = bf16_bits(v.w);
            ((ushort4*)(xh + base))[c] = h;
        }
        s += __shfl_xor(s, 1, 64);
        s += __shfl_xor(s, 2, 64);
        if ((gid & 3) == 0) nrm[gid >> 2] = s;
        return;
    }

    // ---------------- prep path ----------------
    __shared__ float Y[64 * YS];                      // D^T -> Q^T (in place)
    __shared__ __align__(16) float G[64 * GS + 64];   // gram -> L; tail = 1/L[i][i]
    __shared__ __align__(16) float Lti[8 * 8 * 8];    // 8x8 diag-block inverses
    const int n = blockIdx.x;
    const float* Dn = D + (size_t)n * 8192;

    // Phase A: Y[j][c] = Dn[c][j]
    for (int e4 = t; e4 < 2048; e4 += 256) {
        const int c = e4 >> 4, j4 = (e4 & 15) * 4;
        const f32x4 v = ((const f32x4*)Dn)[e4];
        Y[(j4 + 0) * YS + c] = v.x;
        Y[(j4 + 1) * YS + c] = v.y;
        Y[(j4 + 2) * YS + c] = v.z;
        Y[(j4 + 3) * YS + c] = v.w;
    }

    // Phase B: gram from global (L1-hot)
    {
        const int a0 = (t & 15) * 4, b0 = (t >> 4) * 4;
        float acc[4][4] = {};
        #pragma unroll 4
        for (int i = 0; i < 128; ++i) {
            const f32x4 av = *(const f32x4*)(Dn + i * 64 + a0);
            const f32x4 bv = *(const f32x4*)(Dn + i * 64 + b0);
            const float aa[4] = {av.x, av.y, av.z, av.w};
            const float bb[4] = {bv.x, bv.y, bv.z, bv.w};
            #pragma unroll
            for (int p = 0; p < 4; ++p)
                #pragma unroll
                for (int q = 0; q < 4; ++q) acc[p][q] = fmaf(aa[p], bb[q], acc[p][q]);
        }
        #pragma unroll
        for (int p = 0; p < 4; ++p)
            #pragma unroll
            for (int q = 0; q < 4; ++q) G[(a0 + p) * GS + b0 + q] = acc[p][q];
    }
    __syncthreads();

    // Phase C: blocked Cholesky, register-resident 8x8 panels
    for (int p8 = 0; p8 < 8; ++p8) {
        const int pb = p8 * 8;
        if (t < 64) {
            const int lane = t;
            const f32x4 v0 = *(const f32x4*)&G[lane * GS + pb];
            const f32x4 v1 = *(const f32x4*)&G[lane * GS + pb + 4];
            float g[8] = {v0.x, v0.y, v0.z, v0.w, v1.x, v1.y, v1.z, v1.w};
            #pragma unroll
            for (int kk = 0; kk < 8; ++kk) {
                const int k = pb + kk;
                const float dk = __shfl(g[kk], k, 64);
                const float rinv = 1.0f / sqrtf(dk);
                const float lik = g[kk] * rinv;
                g[kk] = lik;
                if (lane == 0) G[64 * GS + k] = rinv;
                #pragma unroll
                for (int jj = kk + 1; jj < 8; ++jj) {
                    const float ljk = __shfl(lik, pb + jj, 64);
                    g[jj] -= lik * ljk;
                }
            }
            *(f32x4*)&G[lane * GS + pb]     = (f32x4){g[0], g[1], g[2], g[3]};
            *(f32x4*)&G[lane * GS + pb + 4] = (f32x4){g[4], g[5], g[6], g[7]};
        }
        __syncthreads();
        const int base = pb + 8;
        if (base < 64) {
            for (int i = base + (t >> 5); i < 64; i += 8) {
                const f32x4 Li0 = *(const f32x4*)&G[i * GS + pb];
                const f32x4 Li1 = *(const f32x4*)&G[i * GS + pb + 4];
                for (int j = base + (t & 31); j < 64; j += 32) {
                    const f32x4 Lj0 = *(const f32x4*)&G[j * GS + pb];
                    const f32x4 Lj1 = *(const f32x4*)&G[j * GS + pb + 4];
                    float s = G[i * GS + j];
                    s -= Li0.x * Lj0.x + Li0.y * Lj0.y + Li0.z * Lj0.z + Li0.w * Lj0.w;
                    s -= Li1.x * Lj1.x + Li1.y * Lj1.y + Li1.z * Lj1.z + Li1.w * Lj1.w;
                    G[i * GS + j] = s;
                }
            }
        }
        __syncthreads();
    }

    // Phase D: invert 8x8 diagonal blocks
    if (t < 64) {
        const int bi = t >> 3, c = t & 7;
        const int base = bi * 8;
        float m[8];
        #pragma unroll
        for (int r = 0; r < 8; ++r) {
            float s = (r == c) ? 1.0f : 0.0f;
            #pragma unroll
            for (int k = 0; k < r; ++k)
                s -= G[(base + r) * GS + base + k] * m[k];
            m[r] = s * G[64 * GS + base + r];
        }
        #pragma unroll
        for (int r = 0; r < 8; ++r) Lti[(base + r) * 8 + c] = m[r];
    }
    __syncthreads();

    // Phase E: block forward substitution, thread = column
    if (t < 128) {
        const int c = t;
        for (int i = 0; i < 8; ++i) {
            float Tv[8];
            #pragma unroll
            for (int r = 0; r < 8; ++r) Tv[r] = Y[(i * 8 + r) * YS + c];
            for (int k = 0; k < i; ++k) {
                #pragma unroll
                for (int kk = 0; kk < 8; ++kk) {
                    const float z = Y[(k * 8 + kk) * YS + c];
                    #pragma unroll
                    for (int r = 0; r < 8; ++r)
                        Tv[r] -= G[(i * 8 + r) * GS + k * 8 + kk] * z;
                }
            }
            #pragma unroll
            for (int r = 0; r < 8; ++r) {
                float z = 0.0f;
                #pragma unroll
                for (int rp = 0; rp <= r; ++rp)
                    z += Lti[(i * 8 + r) * 8 + rp] * Tv[rp];
                Y[(i * 8 + r) * YS + c] = z;
            }
        }
    }
    __syncthreads();

    // Phase F: outputs
    for (int e = t; e < 8192; e += 256) {
        const int j = e >> 7, i = e & 127;
        Bht[((size_t)n * 64 + j) * 128 + i] = bf16_bits(Y[j * YS + i]);
    }
    for (int e = t; e < 8192; e += 256) {
        const int i = e >> 6, j = e & 63;
        Qg[(size_t)n * 8192 + e] = Y[j * YS + i];
    }
}

// ---------------------------------------------------------------------------
// Kernel 2: MFMA scores. Grid (128 m-tiles, 8 n-splits) = 1024 blocks.
// LDS = A 32 KB + B 16 KB (one cluster per iter) = 48 KB -> 3 blocks/CU
// (R8 had 64 KB -> 2/CU; the barrier-drain cadence needs co-residents).
// Wave tile 32m x 64n: each wave computes FULL clusters (B-frags redundant
// across waves, A-frags register-resident per wave).
// ---------------------------------------------------------------------------
__global__ __launch_bounds__(256) void gemm_scores(const unsigned short* __restrict__ xh,
                                                   const unsigned short* __restrict__ Bht,
                                                   float* __restrict__ S) {
    __shared__ unsigned short ldsA[128 * 128];   // 32 KB
    __shared__ unsigned short ldsB[64 * 128];    // 16 KB
    const int t = threadIdx.x, w = t >> 6, lane = t & 63;
    const int m0 = blockIdx.x * 128;
    const int n0 = blockIdx.y * 8;               // first cluster of this split
    const int lm = lane & 15, lg = lane >> 4;

    // ---- stage A (once) + B tile 0 ----
    {
        const int rl = lane >> 4, p = lane & 15;
        #pragma unroll
        for (int q = 0; q < 8; ++q) {
            const int row = w * 32 + q * 4 + rl;
            const int c = p ^ (row & 15);
            gl_lds16(xh + (size_t)(m0 + row) * 128 + c * 8,
                     &ldsA[(w * 32 + q * 4) * 128]);
        }
        #pragma unroll
        for (int q = 0; q < 4; ++q) {
            const int row = w * 16 + q * 4 + rl;
            const int c = p ^ (row & 15);
            gl_lds16(Bht + ((size_t)n0 * 64 + row) * 128 + c * 8,
                     &ldsB[(w * 16 + q * 4) * 128]);
        }
    }
    __syncthreads();   // A + B0 staged

    // ---- A-frags register-resident: rows w*32 .. w*32+31 ----
    s16x8 af[2][4];
    #pragma unroll
    for (int mt = 0; mt < 2; ++mt) {
        const int r = w * 32 + mt * 16 + lm;
        #pragma unroll
        for (int ks = 0; ks < 4; ++ks) {
            const int p = (ks * 4 + lg) ^ (r & 15);
            af[mt][ks] = *(const s16x8*)&ldsA[r * 128 + p * 8];
        }
    }

    #pragma unroll 1
    for (int it = 0; it < 8; ++it) {
        const int nc = n0 + it;

        // frag reads (all waves read the same 64 B-rows)
        s16x8 bf[4][4];
        #pragma unroll
        for (int nt = 0; nt < 4; ++nt) {
            const int r = nt * 16 + lm;
            #pragma unroll
            for (int ks = 0; ks < 4; ++ks) {
                const int p = (ks * 4 + lg) ^ (r & 15);
                bf[nt][ks] = *(const s16x8*)&ldsB[r * 128 + p * 8];
            }
        }
        __syncthreads();   // reads done -> safe to overwrite ldsB

        if (it < 7) {      // kick next cluster's B tile (drained at end barrier)
            const int rl = lane >> 4, p = lane & 15;
            #pragma unroll
            for (int q = 0; q < 4; ++q) {
                const int row = w * 16 + q * 4 + rl;
                const int c = p ^ (row & 15);
                gl_lds16(Bht + ((size_t)(nc + 1) * 64 + row) * 128 + c * 8,
                         &ldsB[(w * 16 + q * 4) * 128]);
            }
        }

        // MFMAs + epilogue (full cluster per wave, 32 m-rows)
        #pragma unroll
        for (int mt = 0; mt < 2; ++mt) {
            f32x4 acc[4];
            #pragma unroll
            for (int nt = 0; nt < 4; ++nt) acc[nt] = (f32x4){0.f, 0.f, 0.f, 0.f};
            #pragma unroll
            for (int ks = 0; ks < 4; ++ks)
                #pragma unroll
                for (int nt = 0; nt < 4; ++nt)
                    acc[nt] = __builtin_amdgcn_mfma_f32_16x16x32_bf16(
                        af[mt][ks], bf[nt][ks], acc[nt], 0, 0, 0);
            #pragma unroll
            for (int rg = 0; rg < 4; ++rg) {
                float p = 0.0f;
                #pragma unroll
                for (int nt = 0; nt < 4; ++nt) {
                    const float v = acc[nt][rg];
                    p += v * v;
                }
                p += __shfl_xor(p, 1, 64);
                p += __shfl_xor(p, 2, 64);
                p += __shfl_xor(p, 4, 64);
                p += __shfl_xor(p, 8, 64);
                if (lm == 0)
                    S[(size_t)nc * B_N + m0 + w * 32 + mt * 16 + lg * 4 + rg] = p;
            }
        }
        __syncthreads();   // drains the kick -> ldsB = next cluster
    }
}

// ---------------------------------------------------------------------------
// Kernel 3: argmax + loss + exact rescore. 512 blocks x 32 samples
// (R9 had 256x64; halves the per-block latency chain).
// ---------------------------------------------------------------------------
__global__ __launch_bounds__(256) void argmax_rescore(const float* __restrict__ Sa,
                                                      const float* __restrict__ nrm,
                                                      const float* __restrict__ x,
                                                      const float* __restrict__ Qg,
                                                      float* __restrict__ out) {
    __shared__ float tile[32 * 65];   // [sample][n]
    __shared__ int sflags[32];
    __shared__ int scnt;
    __shared__ float ssum;
    __shared__ float scorr[4];
    const int t = threadIdx.x, w = t >> 6, lane = t & 63;
    const int b0 = blockIdx.x * 32;
    if (t == 0) scnt = 0;

    // coalesced load + transpose: Sa[n][b0 + c] -> tile[c][n]
    for (int e = t; e < 512; e += 256) {
        const int n = e >> 3, c4 = e & 7;
        const f32x4 v = *(const f32x4*)&Sa[(size_t)n * B_N + b0 + c4 * 4];
        tile[(c4 * 4 + 0) * 65 + n] = v.x;
        tile[(c4 * 4 + 1) * 65 + n] = v.y;
        tile[(c4 * 4 + 2) * 65 + n] = v.z;
        tile[(c4 * 4 + 3) * 65 + n] = v.w;
    }
    __syncthreads();

    // per-thread argmax (threads 0..31), flag near-ties, loss partial
    if (t < 32) {
        float v1 = -1e30f, v2 = -1e30f;
        int n1 = 0;
        for (int n = 0; n < 64; ++n) {
            const float v = tile[t * 65 + n];
            if (v > v1) { v2 = v1; v1 = v; n1 = n; }
            else v2 = fmaxf(v2, v);
        }
        out[1 + b0 + t] = (float)n1;
        if (v1 - v2 < TAU) { const int i = atomicAdd(&scnt, 1); sflags[i] = t; }
        float err = nrm[b0 + t] - v1;
        err += __shfl_xor(err, 1, 64);
        err += __shfl_xor(err, 2, 64);
        err += __shfl_xor(err, 4, 64);
        err += __shfl_xor(err, 8, 64);
        err += __shfl_xor(err, 16, 64);
        if (t == 0) ssum = err;
    }
    if (lane == 0) scorr[w] = 0.0f;
    __syncthreads();

    // cooperative exact rescore of flagged samples (S column from LDS)
    const int nf = scnt;
    float corr = 0.0f;
    for (int f = w; f < nf; f += 4) {
        const int s = sflags[f];
        const int b2 = b0 + s;
        const float v = tile[s * 65 + lane];
        float vm = v;
        for (int off = 32; off; off >>= 1) vm = fmaxf(vm, __shfl_xor(vm, off, 64));
        unsigned long long mask = __ballot((vm - v) < TAU);
        float best = -1e30f;
        int bn = 0;
        while (mask) {
            const int nn = (int)__builtin_ctzll(mask);
            mask &= mask - 1;
            const float* Qn = Qg + (size_t)nn * 8192;
            const float* xb = x + (size_t)b2 * 128;
            float d0 = 0.0f, d1 = 0.0f, d2 = 0.0f, d3 = 0.0f;
            #pragma unroll
            for (int i = 0; i < 128; i += 4) {
                d0 = fmaf(Qn[(i + 0) * 64 + lane], xb[i + 0], d0);
                d1 = fmaf(Qn[(i + 1) * 64 + lane], xb[i + 1], d1);
                d2 = fmaf(Qn[(i + 2) * 64 + lane], xb[i + 2], d2);
                d3 = fmaf(Qn[(i + 3) * 64 + lane], xb[i + 3], d3);
            }
            const float dot = (d0 + d1) + (d2 + d3);
            float sv = dot * dot;
            for (int off = 32; off; off >>= 1) sv += __shfl_xor(sv, off, 64);
            if (sv > best) { best = sv; bn = nn; }
        }
        if (lane == 0) {
            out[1 + b2] = (float)bn;
            corr += vm - best;   // replace approx top score with exact best
        }
    }
    if (lane == 0 && corr != 0.0f) scorr[w] += corr;
    __syncthreads();
    if (t == 0)
        atomicAdd(out, ssum + scorr[0] + scorr[1] + scorr[2] + scorr[3]);
}

// ---------------------------------------------------------------------------
extern "C" void kernel_launch(void* const* d_in, const int* in_sizes, int n_in,
                              void* d_out, int out_size, void* d_ws, size_t ws_size,
                              hipStream_t stream) {
    const float* x = (const float*)d_in[0];   // [16384, 128]
    const float* D = (const float*)d_in[1];   // [64, 128, 64]
    float* out = (float*)d_out;               // [1 + 16384]

    char* ws = (char*)d_ws;
    unsigned short* xh  = (unsigned short*)(ws);                 // 4 MB
    unsigned short* Bht = (unsigned short*)(ws + (4u << 20));    // 1 MB
    float* Qg           = (float*)(ws + (5u << 20));             // 2 MB
    float* Sa           = (float*)(ws + (7u << 20));             // 4 MB
    float* nrm          = (float*)(ws + (11u << 20));            // 64 KB

    prep_convert<<<320, 256, 0, stream>>>(x, D, xh, nrm, Qg, Bht, out);
    gemm_scores<<<dim3(128, 8), 256, 0, stream>>>(xh, Bht, Sa);
    argmax_rescore<<<512, 256, 0, stream>>>(Sa, nrm, x, Qg, out);
}